// Round 3
// baseline (2475.970 us; speedup 1.0000x reference)
//
#include <hip/hip_runtime.h>

#define N_S 400000
#define N_F 128
#define N_K 512
#define ITERS 10

typedef __attribute__((ext_vector_type(8))) short short8;
typedef __attribute__((ext_vector_type(4))) float floatx4;

__device__ inline unsigned short f2bf(float f) {
    unsigned int u = __float_as_uint(f);
    unsigned int r = (u + 0x7FFFu + ((u >> 16) & 1u)) >> 16;
    return (unsigned short)r;
}

// v_cvt_pk_bf16_f32: lo16=cvt(lo), hi16=cvt(hi), RNE (same rounding as f2bf)
__device__ inline unsigned int cvt_pk_bf16(float lo, float hi) {
    unsigned int r;
    asm("v_cvt_pk_bf16_f32 %0, %1, %2" : "=v"(r) : "v"(lo), "v"(hi));
    return r;
}

// Swizzled (MFMA-fragment-order) centroid storage, hi-only:
// cluster k, dim d -> frag ((k>>5)*8 + ((k>>4)&1)*4 + (d>>5)), lane quad*16+m, elem j
__device__ inline void put_sw(unsigned short* __restrict__ swhi, int k, int d, float v) {
    int c = k >> 5, mm = k & 31;
    int mt = mm >> 4, m = mm & 15;
    int kt = d >> 5, r = d & 31;
    int quad = r >> 3, j = r & 7;
    int lane = quad * 16 + m;
    int idx = ((c * 8 + mt * 4 + kt) * 64 + lane) * 8 + j;
    swhi[idx] = f2bf(v);
}

// ---------------------------------------------------------------------------
// prep_update (per iter): [optional] cent = ihist>0 ? sums/ihist : cent;
// write fp32 cent, c_sq, swizzled bf16 hi; zero sums/ihist/cursor/inertia.
// ---------------------------------------------------------------------------
__global__ __launch_bounds__(64) void prep_update_kernel(
    const float* __restrict__ src, float* __restrict__ cent,
    float* __restrict__ sums, int* __restrict__ ihist,
    float* __restrict__ c_sq, unsigned short* __restrict__ swhi,
    int* __restrict__ cursor, float* __restrict__ inertia, int do_update) {
    int k = blockIdx.x, lane = threadIdx.x;
    float a, b;
    float cnt = (float)ihist[k];  // prev-iter counts (garbage & unused when it==0)
    if (do_update) {
        float sa = sums[k * N_F + lane], sb = sums[k * N_F + 64 + lane];
        float olda = cent[k * N_F + lane], oldb = cent[k * N_F + 64 + lane];
        a = (cnt > 0.f) ? (sa / cnt) : olda;
        b = (cnt > 0.f) ? (sb / cnt) : oldb;
    } else {
        a = src[k * N_F + lane];
        b = src[k * N_F + 64 + lane];
    }
    cent[k * N_F + lane] = a;
    cent[k * N_F + 64 + lane] = b;
    sums[k * N_F + lane] = 0.f;
    sums[k * N_F + 64 + lane] = 0.f;
    put_sw(swhi, k, lane, a);
    put_sw(swhi, k, lane + 64, b);
    float s = fmaf(a, a, b * b);
#pragma unroll
    for (int off = 32; off > 0; off >>= 1) s += __shfl_down(s, off);
    if (lane == 0) {
        c_sq[k] = s;
        ihist[k] = 0;
        cursor[k] = 0;
        if (k == 0) *inertia = 0.f;
    }
}

// ---------------------------------------------------------------------------
// assign: bf16 MFMA, A streamed global->reg (L2-resident, fragment-ordered)
// with explicit 1-chunk register double-buffer (aA/aB named arrays, fully
// unrolled -> no scratch). B = 64 samples/wave in regs, no barriers in loop.
// argmin on d2' = c_sq - 2*dot; ||x||^2 computed in-register from the
// preamble loads (quads hold disjoint 32-dim slices -> 2x shfl_xor combine).
// ---------------------------------------------------------------------------
#define CHUNK 32
#define NCHUNK (N_K / CHUNK)
#define NTN 4  // n-tiles per wave (64 samples)

// load the 8 A-fragments of chunk (c) into named reg array DST
#define LOAD_A(DST, c)                                   \
    _Pragma("unroll")                                    \
    for (int i_ = 0; i_ < 8; ++i_) DST[i_] = ap[(c) * 512 + i_ * 64];

// MFMA + argmin for chunk (c) using named A-reg array AR
#define CHUNK_BODY(AR, c)                                                           \
    {                                                                               \
        floatx4 acc[2][NTN];                                                        \
        _Pragma("unroll") for (int mt = 0; mt < 2; ++mt)                            \
            _Pragma("unroll") for (int nt = 0; nt < NTN; ++nt)                      \
                acc[mt][nt] = (floatx4){0.f, 0.f, 0.f, 0.f};                        \
        _Pragma("unroll") for (int kt = 0; kt < 4; ++kt) {                          \
            _Pragma("unroll") for (int nt = 0; nt < NTN; ++nt) {                    \
                acc[0][nt] = __builtin_amdgcn_mfma_f32_16x16x32_bf16(               \
                    AR[kt], bhi[nt][kt], acc[0][nt], 0, 0, 0);                      \
                acc[1][nt] = __builtin_amdgcn_mfma_f32_16x16x32_bf16(               \
                    AR[4 + kt], bhi[nt][kt], acc[1][nt], 0, 0, 0);                  \
            }                                                                       \
        }                                                                           \
        _Pragma("unroll") for (int mt = 0; mt < 2; ++mt) {                          \
            float4 cs = ((const float4*)csq_s)[(c) * 8 + mt * 4 + quad];            \
            _Pragma("unroll") for (int r = 0; r < 4; ++r) {                         \
                float csr = (r == 0) ? cs.x : (r == 1) ? cs.y : (r == 2) ? cs.z     \
                                                                         : cs.w;    \
                int kg = (c) * CHUNK + mt * 16 + quad * 4 + r;                      \
                _Pragma("unroll") for (int nt = 0; nt < NTN; ++nt) {                \
                    float d2 = fmaf(-2.f, acc[mt][nt][r], csr);                     \
                    if (d2 < best[nt]) { best[nt] = d2; bestk[nt] = kg; }           \
                }                                                                   \
            }                                                                       \
        }                                                                           \
    }

__global__ __launch_bounds__(256, 3) void assign_kernel(
    const float* __restrict__ X,
    const unsigned short* __restrict__ swhi,
    const float* __restrict__ c_sq,
    float* __restrict__ labels,
    float* __restrict__ inertia,
    int* __restrict__ ihist) {
    __shared__ __align__(16) float csq_s[N_K];
    __shared__ int lhist[N_K];
    __shared__ float red[4];

    int t = threadIdx.x;
    int w = t >> 6, l = t & 63;
    int quad = l >> 4, l15 = l & 15;
    long long S0 = (long long)blockIdx.x * 256;

    for (int i = t; i < N_K; i += 256) {
        lhist[i] = 0;
        csq_s[i] = c_sq[i];
    }

    // B fragments (bf16 hi) + in-register x_sq; tail rows clamped.
    short8 bhi[NTN][4];
    float xsqv[NTN];
    long long srow[NTN];
#pragma unroll
    for (int nt = 0; nt < NTN; ++nt) {
        long long s = S0 + w * 64 + nt * 16 + l15;
        srow[nt] = s;
        long long ss = (s < N_S) ? s : (N_S - 1);
        const float4* xp = (const float4*)(X + ss * N_F);
        float sq = 0.f;
#pragma unroll
        for (int kt = 0; kt < 4; ++kt) {
            float4 va = xp[kt * 8 + quad * 2];
            float4 vb = xp[kt * 8 + quad * 2 + 1];
            float f[8] = {va.x, va.y, va.z, va.w, vb.x, vb.y, vb.z, vb.w};
            short8 h;
            unsigned int* hw = (unsigned int*)&h;
            hw[0] = cvt_pk_bf16(f[0], f[1]);
            hw[1] = cvt_pk_bf16(f[2], f[3]);
            hw[2] = cvt_pk_bf16(f[4], f[5]);
            hw[3] = cvt_pk_bf16(f[6], f[7]);
#pragma unroll
            for (int j = 0; j < 8; ++j) sq = fmaf(f[j], f[j], sq);
            bhi[nt][kt] = h;
        }
        // combine the 4 quads' partial sums (same sample across quads)
        sq += __shfl_xor(sq, 16);
        sq += __shfl_xor(sq, 32);
        xsqv[nt] = sq;
    }

    const short8* ap = (const short8*)swhi + l;  // + (c*8 + mt*4 + kt)*64

    short8 aA[8], aB[8];
    LOAD_A(aA, 0);     // chunk-0 loads in flight across the barrier
    __syncthreads();   // csq_s / lhist ready

    float best[NTN];
    int bestk[NTN];
#pragma unroll
    for (int nt = 0; nt < NTN; ++nt) { best[nt] = 3.4e38f; bestk[nt] = 0; }

#pragma unroll
    for (int pp = 0; pp < 8; ++pp) {
        LOAD_A(aB, 2 * pp + 1);      // prefetch odd chunk
        CHUNK_BODY(aA, 2 * pp);      // compute even chunk (hides aB latency)
        if (pp < 7) LOAD_A(aA, 2 * pp + 2);  // prefetch next even chunk
        CHUNK_BODY(aB, 2 * pp + 1);  // compute odd chunk (hides aA latency)
    }

    // combine 4 quads per sample column (tie -> smaller k)
#pragma unroll
    for (int nt = 0; nt < NTN; ++nt) {
#pragma unroll
        for (int off = 16; off < 64; off <<= 1) {
            float ob = __shfl_xor(best[nt], off);
            int ok = __shfl_xor(bestk[nt], off);
            if (ob < best[nt] || (ob == best[nt] && ok < bestk[nt])) {
                best[nt] = ob;
                bestk[nt] = ok;
            }
        }
    }

    float contrib = 0.f;
    if (quad == 0) {
#pragma unroll
        for (int nt = 0; nt < NTN; ++nt) {
            if (srow[nt] < N_S) {
                labels[srow[nt]] = (float)bestk[nt];
                atomicAdd(&lhist[bestk[nt]], 1);
                contrib += fmaxf(xsqv[nt] + best[nt], 0.f);
            }
        }
    }
#pragma unroll
    for (int off = 32; off > 0; off >>= 1) contrib += __shfl_down(contrib, off);
    if (l == 0) red[w] = contrib;
    __syncthreads();
    if (t == 0) atomicAdd(inertia, red[0] + red[1] + red[2] + red[3]);

    for (int i = t; i < N_K; i += 256) {
        int v = lhist[i];
        if (v) atomicAdd(&ihist[i], v);
    }
}

// ---------------------------------------------------------------------------
// scatter (per iter): block-aggregated counting-sort scatter, 4 samples/thread.
// Each block redundantly computes the exclusive prefix of ihist in LDS.
// ---------------------------------------------------------------------------
__global__ __launch_bounds__(256) void scatter_kernel(const float* __restrict__ labels,
                                                      const int* __restrict__ ihist,
                                                      int* __restrict__ cursor,
                                                      int* __restrict__ order) {
    __shared__ int lhist[N_K];
    __shared__ int excl[N_K];
    __shared__ int lbase[N_K];
    __shared__ int wtot[4];
    int t = threadIdx.x;
    long long i0 = (long long)blockIdx.x * 1024 + (long long)t * 4;

    for (int j = t; j < N_K; j += 256) lhist[j] = 0;

    // exclusive prefix of ihist[512] with 256 threads (2 entries each)
    int v0 = ihist[2 * t], v1 = ihist[2 * t + 1];
    int s = v0 + v1;
    int x = s;
    int lane = t & 63, w = t >> 6;
#pragma unroll
    for (int off = 1; off < 64; off <<= 1) {
        int y = __shfl_up(x, off);
        if (lane >= off) x += y;
    }
    if (lane == 63) wtot[w] = x;
    __syncthreads();  // lhist zeroed + wtot ready
    int woff = 0;
    for (int ww = 0; ww < w; ++ww) woff += wtot[ww];
    int ex = woff + x - s;
    excl[2 * t] = ex;
    excl[2 * t + 1] = ex + v0;

    int k0 = 0, k1 = 0, k2 = 0, k3 = 0, r0 = 0, r1 = 0, r2 = 0, r3 = 0;
    bool valid = (i0 < N_S);  // N_S % 4 == 0 -> whole quad valid or not
    if (valid) {
        float4 lab = *(const float4*)(labels + i0);
        k0 = (int)lab.x; k1 = (int)lab.y; k2 = (int)lab.z; k3 = (int)lab.w;
        r0 = atomicAdd(&lhist[k0], 1);
        r1 = atomicAdd(&lhist[k1], 1);
        r2 = atomicAdd(&lhist[k2], 1);
        r3 = atomicAdd(&lhist[k3], 1);
    }
    __syncthreads();  // lhist final + excl written
    for (int j = t; j < N_K; j += 256) {
        int c = lhist[j];
        lbase[j] = c ? (excl[j] + atomicAdd(&cursor[j], c)) : 0;
    }
    __syncthreads();
    if (valid) {
        order[lbase[k0] + r0] = (int)i0;
        order[lbase[k1] + r1] = (int)i0 + 1;
        order[lbase[k2] + r2] = (int)i0 + 2;
        order[lbase[k3] + r3] = (int)i0 + 3;
    }
}

// ---------------------------------------------------------------------------
// csum (per iter): float4 gather-accumulate over order[] windows.
// 8 row-groups x 32 dim-threads per block; cluster id from labels[order[r]].
// Tail rows -> sentinel cluster N_K (dummy row).
// ---------------------------------------------------------------------------
#define RPB 256
#define RPG 32

__device__ inline void flush4(float* __restrict__ sums, int k, int dbase, float4 acc) {
    float* sp = sums + k * N_F + dbase;
    atomicAdd(sp + 0, acc.x);
    atomicAdd(sp + 1, acc.y);
    atomicAdd(sp + 2, acc.z);
    atomicAdd(sp + 3, acc.w);
}

__global__ __launch_bounds__(256) void csum_kernel(const float* __restrict__ X,
                                                   const int* __restrict__ order,
                                                   const float* __restrict__ labels,
                                                   float* __restrict__ sums) {
    __shared__ int ord_s[RPB];
    __shared__ int k_s[RPB];
    int t = threadIdx.x;
    long long r0 = (long long)blockIdx.x * RPB;
    bool vrow = (r0 + t) < N_S;
    int o = vrow ? order[r0 + t] : 0;
    ord_s[t] = o;
    k_s[t] = vrow ? (int)labels[o] : N_K;  // sentinel -> dummy sums row
    __syncthreads();

    int g = t >> 5;              // 8 groups of 32 rows
    int dbase = (t & 31) << 2;   // 4 dims per thread
    const float* Xd = X + dbase;
    int base = g * RPG;

    float4 acc = {0.f, 0.f, 0.f, 0.f};
    int kcur = k_s[base];
    if (kcur == k_s[base + RPG - 1]) {
        // fast path: whole group range is one cluster
#pragma unroll 8
        for (int i = 0; i < RPG; ++i) {
            const float4 v = *(const float4*)(Xd + (long long)ord_s[base + i] * N_F);
            acc.x += v.x; acc.y += v.y; acc.z += v.z; acc.w += v.w;
        }
        flush4(sums, kcur, dbase, acc);
    } else {
        for (int i = 0; i < RPG; ++i) {
            int k = k_s[base + i];
            if (k != kcur) {
                flush4(sums, kcur, dbase, acc);
                acc = (float4){0.f, 0.f, 0.f, 0.f};
                kcur = k;
            }
            const float4 v = *(const float4*)(Xd + (long long)ord_s[base + i] * N_F);
            acc.x += v.x; acc.y += v.y; acc.z += v.z; acc.w += v.w;
        }
        flush4(sums, kcur, dbase, acc);
    }
}

// ---------------------------------------------------------------------------
// final update: cent = ihist>0 ? sums/ihist : cent
// ---------------------------------------------------------------------------
__global__ __launch_bounds__(128) void update_kernel(const float* __restrict__ sums,
                                                     const int* __restrict__ ihist,
                                                     float* __restrict__ cent) {
    int k = blockIdx.x;
    int d = threadIdx.x;
    float c = (float)ihist[k];
    float s = sums[k * N_F + d];
    float old = cent[k * N_F + d];
    cent[k * N_F + d] = (c > 0.f) ? (s / c) : old;
}

extern "C" void kernel_launch(void* const* d_in, const int* in_sizes, int n_in,
                              void* d_out, int out_size, void* d_ws, size_t ws_size,
                              hipStream_t stream) {
    const float* X = (const float*)d_in[0];
    const float* initc = (const float*)d_in[1];

    float* out = (float*)d_out;
    float* cent = out;                // [512*128] (output 0)
    float* labels = out + N_K * N_F;  // [400000]  (output 1)
    float* inertia = labels + N_S;    // [1]       (output 2)

    float* c_sq = (float*)d_ws;                           // 512 f
    float* sums = c_sq + N_K;                             // (512+1)*128 f (dummy row for tail)
    unsigned short* swhi = (unsigned short*)(sums + (N_K + 1) * N_F);  // 65536 ush
    int* ihist = (int*)(swhi + N_K * N_F);                // 512 i
    int* cursor = ihist + N_K;                            // 512 i
    int* order = cursor + N_K;                            // 400000 i

    for (int it = 0; it < ITERS; ++it) {
        prep_update_kernel<<<N_K, 64, 0, stream>>>(initc, cent, sums, ihist, c_sq,
                                                   swhi, cursor, inertia, it > 0);
        assign_kernel<<<(N_S + 255) / 256, 256, 0, stream>>>(X, swhi, c_sq,
                                                             labels, inertia, ihist);
        scatter_kernel<<<(N_S + 1023) / 1024, 256, 0, stream>>>(labels, ihist, cursor, order);
        csum_kernel<<<(N_S + RPB - 1) / RPB, 256, 0, stream>>>(X, order, labels, sums);
    }
    update_kernel<<<N_K, N_F, 0, stream>>>(sums, ihist, cent);
}

// Round 4
// 1809.939 us; speedup vs baseline: 1.3680x; 1.3680x over previous
//
#include <hip/hip_runtime.h>

#define N_S 400000
#define N_F 128
#define N_K 512
#define ITERS 10

typedef __attribute__((ext_vector_type(8))) short short8;
typedef __attribute__((ext_vector_type(4))) float floatx4;

__device__ inline unsigned short f2bf(float f) {
    unsigned int u = __float_as_uint(f);
    unsigned int r = (u + 0x7FFFu + ((u >> 16) & 1u)) >> 16;
    return (unsigned short)r;
}

// v_cvt_pk_bf16_f32: lo16=cvt(lo), hi16=cvt(hi), RNE (same rounding as f2bf)
__device__ inline unsigned int cvt_pk_bf16(float lo, float hi) {
    unsigned int r;
    asm("v_cvt_pk_bf16_f32 %0, %1, %2" : "=v"(r) : "v"(lo), "v"(hi));
    return r;
}

// async global->LDS, 16B per lane, zero VGPR round-trip
__device__ inline void gload_lds16(const void* g, void* l) {
    __builtin_amdgcn_global_load_lds(
        (const __attribute__((address_space(1))) void*)g,
        (__attribute__((address_space(3))) void*)l, 16, 0, 0);
}

// Swizzled (MFMA-fragment-order) centroid storage, hi-only:
// cluster k, dim d -> frag ((k>>5)*8 + ((k>>4)&1)*4 + (d>>5)), lane quad*16+m, elem j
__device__ inline void put_sw(unsigned short* __restrict__ swhi, int k, int d, float v) {
    int c = k >> 5, mm = k & 31;
    int mt = mm >> 4, m = mm & 15;
    int kt = d >> 5, r = d & 31;
    int quad = r >> 3, j = r & 7;
    int lane = quad * 16 + m;
    int idx = ((c * 8 + mt * 4 + kt) * 64 + lane) * 8 + j;
    swhi[idx] = f2bf(v);
}

// ---------------------------------------------------------------------------
// prep_update (per iter): [optional] cent = ihist>0 ? sums/ihist : cent;
// write fp32 cent, c_sq, swizzled bf16 hi; zero sums/ihist/cursor/inertia.
// ---------------------------------------------------------------------------
__global__ __launch_bounds__(64) void prep_update_kernel(
    const float* __restrict__ src, float* __restrict__ cent,
    float* __restrict__ sums, int* __restrict__ ihist,
    float* __restrict__ c_sq, unsigned short* __restrict__ swhi,
    int* __restrict__ cursor, float* __restrict__ inertia, int do_update) {
    int k = blockIdx.x, lane = threadIdx.x;
    float a, b;
    float cnt = (float)ihist[k];  // prev-iter counts (garbage & unused when it==0)
    if (do_update) {
        float sa = sums[k * N_F + lane], sb = sums[k * N_F + 64 + lane];
        float olda = cent[k * N_F + lane], oldb = cent[k * N_F + 64 + lane];
        a = (cnt > 0.f) ? (sa / cnt) : olda;
        b = (cnt > 0.f) ? (sb / cnt) : oldb;
    } else {
        a = src[k * N_F + lane];
        b = src[k * N_F + 64 + lane];
    }
    cent[k * N_F + lane] = a;
    cent[k * N_F + 64 + lane] = b;
    sums[k * N_F + lane] = 0.f;
    sums[k * N_F + 64 + lane] = 0.f;
    put_sw(swhi, k, lane, a);
    put_sw(swhi, k, lane + 64, b);
    float s = fmaf(a, a, b * b);
#pragma unroll
    for (int off = 32; off > 0; off >>= 1) s += __shfl_down(s, off);
    if (lane == 0) {
        c_sq[k] = s;
        ihist[k] = 0;
        cursor[k] = 0;
        if (k == 0) *inertia = 0.f;
    }
}

// ---------------------------------------------------------------------------
// assign: bf16 MFMA. A-table (128KB, fragment-ordered) double-buffered
// through LDS in 32KB quarters via global_load_lds (async DMA, zero VGPRs).
// Per phase: issue next quarter's DMA, compute 4 chunks from current buffer
// (ds_read_b128 + MFMA + argmin), one barrier (drains vmcnt).
// B = 64 samples/wave in regs. argmin on d2' = c_sq - 2*dot; ||x||^2
// computed in-register from the preamble loads (quads hold disjoint 32-dim
// slices -> 2x shfl_xor combine).
// ---------------------------------------------------------------------------
#define CHUNK 32
#define NCHUNK (N_K / CHUNK)
#define NTN 4  // n-tiles per wave (64 samples)

__global__ __launch_bounds__(256, 2) void assign_kernel(
    const float* __restrict__ X,
    const unsigned short* __restrict__ swhi,
    const float* __restrict__ c_sq,
    float* __restrict__ labels,
    float* __restrict__ inertia,
    int* __restrict__ ihist) {
    __shared__ __align__(16) short8 a_lds[2][4 * 8 * 64];  // 2 x 32KB quarters
    __shared__ __align__(16) float csq_s[N_K];
    __shared__ int lhist[N_K];
    __shared__ float red[4];

    int t = threadIdx.x;
    int w = t >> 6, l = t & 63;
    int quad = l >> 4, l15 = l & 15;
    long long S0 = (long long)blockIdx.x * 256;

    // kick off quarter-0 DMA first (overlaps with everything below)
    {
        const char* gq = (const char*)swhi + t * 16;
        char* lq = (char*)a_lds[0] + t * 16;
#pragma unroll
        for (int i = 0; i < 8; ++i) gload_lds16(gq + i * 4096, lq + i * 4096);
    }

    for (int i = t; i < N_K; i += 256) {
        lhist[i] = 0;
        csq_s[i] = c_sq[i];
    }

    // B fragments (bf16 hi) + in-register x_sq; tail rows clamped.
    short8 bhi[NTN][4];
    float xsqv[NTN];
    long long srow[NTN];
#pragma unroll
    for (int nt = 0; nt < NTN; ++nt) {
        long long s = S0 + w * 64 + nt * 16 + l15;
        srow[nt] = s;
        long long ss = (s < N_S) ? s : (N_S - 1);
        const float4* xp = (const float4*)(X + ss * N_F);
        float sq = 0.f;
#pragma unroll
        for (int kt = 0; kt < 4; ++kt) {
            float4 va = xp[kt * 8 + quad * 2];
            float4 vb = xp[kt * 8 + quad * 2 + 1];
            float f[8] = {va.x, va.y, va.z, va.w, vb.x, vb.y, vb.z, vb.w};
            short8 h;
            unsigned int* hw = (unsigned int*)&h;
            hw[0] = cvt_pk_bf16(f[0], f[1]);
            hw[1] = cvt_pk_bf16(f[2], f[3]);
            hw[2] = cvt_pk_bf16(f[4], f[5]);
            hw[3] = cvt_pk_bf16(f[6], f[7]);
#pragma unroll
            for (int j = 0; j < 8; ++j) sq = fmaf(f[j], f[j], sq);
            bhi[nt][kt] = h;
        }
        // combine the 4 quads' partial sums (same sample across quads)
        sq += __shfl_xor(sq, 16);
        sq += __shfl_xor(sq, 32);
        xsqv[nt] = sq;
    }

    __syncthreads();  // drains vmcnt (q0 DMA + X loads), csq_s/lhist ready

    float best[NTN];
    int bestk[NTN];
#pragma unroll
    for (int nt = 0; nt < NTN; ++nt) { best[nt] = 3.4e38f; bestk[nt] = 0; }

#pragma unroll
    for (int p = 0; p < 4; ++p) {
        // issue next quarter's DMA (async; hidden under this quarter's compute)
        if (p < 3) {
            const char* gq = (const char*)swhi + (p + 1) * 32768 + t * 16;
            char* lq = (char*)a_lds[(p + 1) & 1] + t * 16;
#pragma unroll
            for (int i = 0; i < 8; ++i) gload_lds16(gq + i * 4096, lq + i * 4096);
        }

        const short8* abase = a_lds[p & 1] + l;
#pragma unroll
        for (int cc = 0; cc < 4; ++cc) {
            int c = p * 4 + cc;
            floatx4 acc[2][NTN];
#pragma unroll
            for (int mt = 0; mt < 2; ++mt)
#pragma unroll
                for (int nt = 0; nt < NTN; ++nt) acc[mt][nt] = (floatx4){0.f, 0.f, 0.f, 0.f};

#pragma unroll
            for (int kt = 0; kt < 4; ++kt) {
                short8 a0 = abase[(cc * 8 + kt) * 64];
                short8 a1 = abase[(cc * 8 + 4 + kt) * 64];
#pragma unroll
                for (int nt = 0; nt < NTN; ++nt) {
                    acc[0][nt] = __builtin_amdgcn_mfma_f32_16x16x32_bf16(a0, bhi[nt][kt], acc[0][nt], 0, 0, 0);
                    acc[1][nt] = __builtin_amdgcn_mfma_f32_16x16x32_bf16(a1, bhi[nt][kt], acc[1][nt], 0, 0, 0);
                }
            }

#pragma unroll
            for (int mt = 0; mt < 2; ++mt) {
                float4 cs = ((const float4*)csq_s)[c * 8 + mt * 4 + quad];
#pragma unroll
                for (int r = 0; r < 4; ++r) {
                    float csr = (r == 0) ? cs.x : (r == 1) ? cs.y : (r == 2) ? cs.z : cs.w;
                    int kg = c * CHUNK + mt * 16 + quad * 4 + r;
#pragma unroll
                    for (int nt = 0; nt < NTN; ++nt) {
                        float d2 = fmaf(-2.f, acc[mt][nt][r], csr);
                        if (d2 < best[nt]) { best[nt] = d2; bestk[nt] = kg; }
                    }
                }
            }
        }

        if (p < 3) __syncthreads();  // stage of p+1 landed; all done reading buf[p&1]
    }

    // combine 4 quads per sample column (tie -> smaller k)
#pragma unroll
    for (int nt = 0; nt < NTN; ++nt) {
#pragma unroll
        for (int off = 16; off < 64; off <<= 1) {
            float ob = __shfl_xor(best[nt], off);
            int ok = __shfl_xor(bestk[nt], off);
            if (ob < best[nt] || (ob == best[nt] && ok < bestk[nt])) {
                best[nt] = ob;
                bestk[nt] = ok;
            }
        }
    }

    float contrib = 0.f;
    if (quad == 0) {
#pragma unroll
        for (int nt = 0; nt < NTN; ++nt) {
            if (srow[nt] < N_S) {
                labels[srow[nt]] = (float)bestk[nt];
                atomicAdd(&lhist[bestk[nt]], 1);
                contrib += fmaxf(xsqv[nt] + best[nt], 0.f);
            }
        }
    }
#pragma unroll
    for (int off = 32; off > 0; off >>= 1) contrib += __shfl_down(contrib, off);
    if (l == 0) red[w] = contrib;
    __syncthreads();
    if (t == 0) atomicAdd(inertia, red[0] + red[1] + red[2] + red[3]);

    for (int i = t; i < N_K; i += 256) {
        int v = lhist[i];
        if (v) atomicAdd(&ihist[i], v);
    }
}

// ---------------------------------------------------------------------------
// scatter (per iter): block-aggregated counting-sort scatter, 4 samples/thread.
// Each block redundantly computes the exclusive prefix of ihist in LDS.
// ---------------------------------------------------------------------------
__global__ __launch_bounds__(256) void scatter_kernel(const float* __restrict__ labels,
                                                      const int* __restrict__ ihist,
                                                      int* __restrict__ cursor,
                                                      int* __restrict__ order) {
    __shared__ int lhist[N_K];
    __shared__ int excl[N_K];
    __shared__ int lbase[N_K];
    __shared__ int wtot[4];
    int t = threadIdx.x;
    long long i0 = (long long)blockIdx.x * 1024 + (long long)t * 4;

    for (int j = t; j < N_K; j += 256) lhist[j] = 0;

    // exclusive prefix of ihist[512] with 256 threads (2 entries each)
    int v0 = ihist[2 * t], v1 = ihist[2 * t + 1];
    int s = v0 + v1;
    int x = s;
    int lane = t & 63, w = t >> 6;
#pragma unroll
    for (int off = 1; off < 64; off <<= 1) {
        int y = __shfl_up(x, off);
        if (lane >= off) x += y;
    }
    if (lane == 63) wtot[w] = x;
    __syncthreads();  // lhist zeroed + wtot ready
    int woff = 0;
    for (int ww = 0; ww < w; ++ww) woff += wtot[ww];
    int ex = woff + x - s;
    excl[2 * t] = ex;
    excl[2 * t + 1] = ex + v0;

    int k0 = 0, k1 = 0, k2 = 0, k3 = 0, r0 = 0, r1 = 0, r2 = 0, r3 = 0;
    bool valid = (i0 < N_S);  // N_S % 4 == 0 -> whole quad valid or not
    if (valid) {
        float4 lab = *(const float4*)(labels + i0);
        k0 = (int)lab.x; k1 = (int)lab.y; k2 = (int)lab.z; k3 = (int)lab.w;
        r0 = atomicAdd(&lhist[k0], 1);
        r1 = atomicAdd(&lhist[k1], 1);
        r2 = atomicAdd(&lhist[k2], 1);
        r3 = atomicAdd(&lhist[k3], 1);
    }
    __syncthreads();  // lhist final + excl written
    for (int j = t; j < N_K; j += 256) {
        int c = lhist[j];
        lbase[j] = c ? (excl[j] + atomicAdd(&cursor[j], c)) : 0;
    }
    __syncthreads();
    if (valid) {
        order[lbase[k0] + r0] = (int)i0;
        order[lbase[k1] + r1] = (int)i0 + 1;
        order[lbase[k2] + r2] = (int)i0 + 2;
        order[lbase[k3] + r3] = (int)i0 + 3;
    }
}

// ---------------------------------------------------------------------------
// csum (per iter): float4 gather-accumulate over order[] windows.
// 8 row-groups x 32 dim-threads per block; cluster id from labels[order[r]].
// Tail rows -> sentinel cluster N_K (dummy row).
// ---------------------------------------------------------------------------
#define RPB 256
#define RPG 32

__device__ inline void flush4(float* __restrict__ sums, int k, int dbase, float4 acc) {
    float* sp = sums + k * N_F + dbase;
    atomicAdd(sp + 0, acc.x);
    atomicAdd(sp + 1, acc.y);
    atomicAdd(sp + 2, acc.z);
    atomicAdd(sp + 3, acc.w);
}

__global__ __launch_bounds__(256) void csum_kernel(const float* __restrict__ X,
                                                   const int* __restrict__ order,
                                                   const float* __restrict__ labels,
                                                   float* __restrict__ sums) {
    __shared__ int ord_s[RPB];
    __shared__ int k_s[RPB];
    int t = threadIdx.x;
    long long r0 = (long long)blockIdx.x * RPB;
    bool vrow = (r0 + t) < N_S;
    int o = vrow ? order[r0 + t] : 0;
    ord_s[t] = o;
    k_s[t] = vrow ? (int)labels[o] : N_K;  // sentinel -> dummy sums row
    __syncthreads();

    int g = t >> 5;              // 8 groups of 32 rows
    int dbase = (t & 31) << 2;   // 4 dims per thread
    const float* Xd = X + dbase;
    int base = g * RPG;

    float4 acc = {0.f, 0.f, 0.f, 0.f};
    int kcur = k_s[base];
    if (kcur == k_s[base + RPG - 1]) {
        // fast path: whole group range is one cluster
#pragma unroll 8
        for (int i = 0; i < RPG; ++i) {
            const float4 v = *(const float4*)(Xd + (long long)ord_s[base + i] * N_F);
            acc.x += v.x; acc.y += v.y; acc.z += v.z; acc.w += v.w;
        }
        flush4(sums, kcur, dbase, acc);
    } else {
        for (int i = 0; i < RPG; ++i) {
            int k = k_s[base + i];
            if (k != kcur) {
                flush4(sums, kcur, dbase, acc);
                acc = (float4){0.f, 0.f, 0.f, 0.f};
                kcur = k;
            }
            const float4 v = *(const float4*)(Xd + (long long)ord_s[base + i] * N_F);
            acc.x += v.x; acc.y += v.y; acc.z += v.z; acc.w += v.w;
        }
        flush4(sums, kcur, dbase, acc);
    }
}

// ---------------------------------------------------------------------------
// final update: cent = ihist>0 ? sums/ihist : cent
// ---------------------------------------------------------------------------
__global__ __launch_bounds__(128) void update_kernel(const float* __restrict__ sums,
                                                     const int* __restrict__ ihist,
                                                     float* __restrict__ cent) {
    int k = blockIdx.x;
    int d = threadIdx.x;
    float c = (float)ihist[k];
    float s = sums[k * N_F + d];
    float old = cent[k * N_F + d];
    cent[k * N_F + d] = (c > 0.f) ? (s / c) : old;
}

extern "C" void kernel_launch(void* const* d_in, const int* in_sizes, int n_in,
                              void* d_out, int out_size, void* d_ws, size_t ws_size,
                              hipStream_t stream) {
    const float* X = (const float*)d_in[0];
    const float* initc = (const float*)d_in[1];

    float* out = (float*)d_out;
    float* cent = out;                // [512*128] (output 0)
    float* labels = out + N_K * N_F;  // [400000]  (output 1)
    float* inertia = labels + N_S;    // [1]       (output 2)

    float* c_sq = (float*)d_ws;                           // 512 f
    float* sums = c_sq + N_K;                             // (512+1)*128 f (dummy row for tail)
    unsigned short* swhi = (unsigned short*)(sums + (N_K + 1) * N_F);  // 65536 ush
    int* ihist = (int*)(swhi + N_K * N_F);                // 512 i
    int* cursor = ihist + N_K;                            // 512 i
    int* order = cursor + N_K;                            // 400000 i

    for (int it = 0; it < ITERS; ++it) {
        prep_update_kernel<<<N_K, 64, 0, stream>>>(initc, cent, sums, ihist, c_sq,
                                                   swhi, cursor, inertia, it > 0);
        assign_kernel<<<(N_S + 255) / 256, 256, 0, stream>>>(X, swhi, c_sq,
                                                             labels, inertia, ihist);
        scatter_kernel<<<(N_S + 1023) / 1024, 256, 0, stream>>>(labels, ihist, cursor, order);
        csum_kernel<<<(N_S + RPB - 1) / RPB, 256, 0, stream>>>(X, order, labels, sums);
    }
    update_kernel<<<N_K, N_F, 0, stream>>>(sums, ihist, cent);
}